// Round 10
// baseline (124.140 us; speedup 1.0000x reference)
//
#include <hip/hip_runtime.h>

typedef __attribute__((ext_vector_type(8))) int   i32x8;
typedef __attribute__((ext_vector_type(4))) float f32x4;
typedef unsigned int uint32;

constexpr int N = 16384;
constexpr int K = 1024;
constexpr int M = 1024;

#define WAITVM(n) asm volatile("s_waitcnt vmcnt(" #n ")" ::: "memory")
#define FENCE() asm volatile("" ::: "memory")
#define BAR()                          \
    do {                               \
        FENCE();                       \
        __builtin_amdgcn_s_barrier();  \
        FENCE();                       \
    } while (0)

__device__ inline void gload_lds16(const unsigned char* g, unsigned char* l) {
    __builtin_amdgcn_global_load_lds(
        (const __attribute__((address_space(1))) unsigned int*)g,
        (__attribute__((address_space(3))) unsigned int*)l,
        16, 0, 0);
}

// pack 4 f32 -> 4 OCP e4m3 bytes (k-ascending), saturating
__device__ inline uint32 pack4_fp8(float a, float b, float c, float d) {
    int v = __builtin_amdgcn_cvt_pk_fp8_f32(a, b, 0, false);   // bytes 0,1
    v = __builtin_amdgcn_cvt_pk_fp8_f32(c, d, v, true);        // bytes 2,3
    return (uint32)v;
}

// One block per mu row: norm; W8 = mu_n*inv_std*0.25 (fp8); mmh = -0.5*sum(mu_n^2*inv_std)
__global__ void prep_mu(const float* __restrict__ mu, const float* __restrict__ stdv,
                        uint32* __restrict__ Wb8, float* __restrict__ mmh) {
    int m = blockIdx.x;
    int t = threadIdx.x;
    float4 v = ((const float4*)(mu + (size_t)m * K))[t];
    float4 s = ((const float4*)stdv)[t];
    float ix = 1.0f / s.x, iy = 1.0f / s.y, iz = 1.0f / s.z, iw = 1.0f / s.w;
    float sum2  = v.x * v.x + v.y * v.y + v.z * v.z + v.w * v.w;
    float sum2w = v.x * v.x * ix + v.y * v.y * iy + v.z * v.z * iz + v.w * v.w * iw;
    for (int off = 32; off > 0; off >>= 1) {
        sum2  += __shfl_down(sum2, off, 64);
        sum2w += __shfl_down(sum2w, off, 64);
    }
    __shared__ float r2[4], r2w[4];
    __shared__ float s_scale;
    int lane = t & 63, w = t >> 6;
    if (lane == 0) { r2[w] = sum2; r2w[w] = sum2w; }
    __syncthreads();
    if (t == 0) {
        float tot2  = r2[0] + r2[1] + r2[2] + r2[3];
        float tot2w = r2w[0] + r2w[1] + r2w[2] + r2w[3];
        mmh[m] = -0.5f * tot2w / tot2;
        s_scale = rsqrtf(tot2) * 0.25f;        // fold the 1/4 fp8-range scale
    }
    __syncthreads();
    float sc = s_scale;
    Wb8[m * (K / 4) + t] = pack4_fp8(v.x * ix * sc, v.y * iy * sc,
                                     v.z * iz * sc, v.w * iw * sc);
}

// ---------------------------------------------------------------------------
// prep_x: one block per 16-row group g. Emits A' in MFMA-FRAGMENT layout:
//   A'[g][kt][lane][32B], byte j of lane l = fp8(x[g*16+(l&15)][kt*128+(l>>4)*32+j])
// so the GEMM's A-frag load is global dwordx4 at base+lane*32 (fully coalesced,
// no LDS). Also computes xxh[row] = -0.5*sum(x^2/std).
// ---------------------------------------------------------------------------
__global__ __launch_bounds__(256) void prep_x(const float* __restrict__ x,
                                              const float* __restrict__ stdv,
                                              unsigned char* __restrict__ Ap,
                                              float* __restrict__ xxh) {
    int g = blockIdx.x;          // 0..1023
    int t = threadIdx.x;
    int lane = t & 63;
    int row16 = t & 15;
    int lk = (t >> 4) & 3;
    int kt0 = t >> 6;            // 0..3; second slot kt0+4
    const float* xrow = x + ((size_t)g * 16 + row16) * K;
    float p = 0.f;
    __shared__ float part[16][17];
#pragma unroll
    for (int s = 0; s < 2; ++s) {
        int kt = kt0 + 4 * s;
        int c0 = kt * 128 + lk * 32;        // f32 col base; thread covers 32 cols
        uint32 pk[8];
#pragma unroll
        for (int i = 0; i < 8; ++i) {
            float4 v  = *(const float4*)(xrow + c0 + i * 4);
            float4 sv = *(const float4*)(stdv + c0 + i * 4);
            p += v.x * v.x / sv.x + v.y * v.y / sv.y +
                 v.z * v.z / sv.z + v.w * v.w / sv.w;
            pk[i] = pack4_fp8(v.x, v.y, v.z, v.w);
        }
        unsigned char* dst = Ap + (((size_t)g * 8 + kt) * 64 + lane) * 32;
        *(uint4*)dst        = make_uint4(pk[0], pk[1], pk[2], pk[3]);
        *(uint4*)(dst + 16) = make_uint4(pk[4], pk[5], pk[6], pk[7]);
    }
    part[row16][t >> 4] = p;     // both slots are the same row -> one write
    __syncthreads();
    if (t < 16) {
        float ssum = 0.f;
#pragma unroll
        for (int j = 0; j < 16; ++j) ssum += part[t][j];
        xxh[g * 16 + t] = -0.5f * ssum;
    }
}

// ---------------------------------------------------------------------------
// fp8 GEMM, 128x128 tile, 4 waves (2x2, 64x64 each), BK=128 bytes.
// A: fragment-layout A' read STRAIGHT to registers (coalesced dwordx4 at
//    base+lane*32; L2-resident slice per XCD) — no LDS, no staging for A.
//    Register-double-buffered (afA/afB) via 2x-unrolled K loop (rule 20).
// B: global_load_lds dbuf (32 KiB total), slot^(row&7) swizzle (rule 21).
// All waits are vmcnt(0) DRAINS (replay-safe; R5 lesson). 1 barrier/tile.
// C = 4*(A'*B8^T) + xxh[row] + mmh[col]
// ---------------------------------------------------------------------------
#define BKB 128
#define BTILE (128 * BKB)              // 16 KiB per B buffer

__global__ __launch_bounds__(256, 3) void gemm_ep(
    const unsigned char* __restrict__ Ap, const unsigned char* __restrict__ B8,
    const float* __restrict__ xxh, const float* __restrict__ mmh,
    float* __restrict__ C) {
    __shared__ unsigned char Bls[2 * BTILE];   // 32 KiB

    int t = threadIdx.x;
    int lane = t & 63;
    int wave = t >> 6;
    int wr = wave >> 1;          // 0..1
    int wc = wave & 1;           // 0..1
    int r  = lane & 15;
    int lk = lane >> 4;          // k-slot 0..3 (32B each)

    // T1: XCD swizzle, nwg=1024 (bijective: 1024%8==0)
    int bid = blockIdx.x;
    int swz = (bid & 7) * 128 + (bid >> 3);
    int tn = swz >> 3;           // 0..127
    int tm = swz & 7;            // 0..7

    const unsigned char* Bbase = B8 + (size_t)tm * 128 * K;
    // A' group base for this wave: g = tn*8 + wr*4 + mi; group stride 16 KiB
    const unsigned char* Abase = Ap + (((size_t)tn * 8 + wr * 4) * 8) * 2048;

    f32x4 acc[4][4] = {};
    i32x8 afA[4], afB[4], bf[4];

    // stage one 128x128B B tile: 1024 16B chunks, 4 per thread.
    // lds row=c>>3, slot=c&7; SOURCE slot pre-swizzled ^(row&7) (rule 21).
#define STAGE_B(kt_, buf_)                                                     \
    {                                                                          \
        const unsigned char* g_ = Bbase + (size_t)(kt_) * BKB;                 \
        unsigned char* l_ = Bls + (buf_) * BTILE;                              \
        _Pragma("unroll")                                                      \
        for (int i_ = 0; i_ < 4; ++i_) {                                       \
            int c_ = i_ * 256 + t;                                             \
            int row_ = c_ >> 3;                                                \
            int slot_ = (c_ & 7) ^ (row_ & 7);                                 \
            gload_lds16(g_ + (size_t)row_ * K + slot_ * 16,                    \
                        l_ + (i_ * 256 + (wave << 6)) * 16);                   \
        }                                                                      \
    }

    // A fragments: coalesced global loads from fragment-layout A'
#define LOAD_AF(dst_, kt_)                                                     \
    _Pragma("unroll")                                                          \
    for (int mi_ = 0; mi_ < 4; ++mi_) {                                        \
        const unsigned char* ga_ =                                             \
            Abase + ((size_t)mi_ * 8 + (kt_)) * 2048 + lane * 32;              \
        uint4 q0_ = *(const uint4*)ga_;                                        \
        uint4 q1_ = *(const uint4*)(ga_ + 16);                                 \
        dst_[mi_][0] = q0_.x; dst_[mi_][1] = q0_.y;                            \
        dst_[mi_][2] = q0_.z; dst_[mi_][3] = q0_.w;                            \
        dst_[mi_][4] = q1_.x; dst_[mi_][5] = q1_.y;                            \
        dst_[mi_][6] = q1_.z; dst_[mi_][7] = q1_.w;                            \
    }

    // B fragments from swizzled LDS: byte slots (2lk|h)^(r&7)
#define LOAD_BF(Bs_)                                                           \
    _Pragma("unroll")                                                          \
    for (int ni_ = 0; ni_ < 4; ++ni_) {                                        \
        int row_ = wc * 64 + ni_ * 16 + r;                                     \
        uint4 q0_ = *(const uint4*)&(Bs_)[(row_ << 7) +                        \
                                          ((((lk << 1) | 0) ^ (r & 7)) << 4)]; \
        uint4 q1_ = *(const uint4*)&(Bs_)[(row_ << 7) +                        \
                                          ((((lk << 1) | 1) ^ (r & 7)) << 4)]; \
        bf[ni_][0] = q0_.x; bf[ni_][1] = q0_.y;                                \
        bf[ni_][2] = q0_.z; bf[ni_][3] = q0_.w;                                \
        bf[ni_][4] = q1_.x; bf[ni_][5] = q1_.y;                                \
        bf[ni_][6] = q1_.z; bf[ni_][7] = q1_.w;                                \
    }

#define MFMA_ALL(af_)                                                          \
    __builtin_amdgcn_s_setprio(1);                                             \
    _Pragma("unroll")                                                          \
    for (int mi_ = 0; mi_ < 4; ++mi_)                                          \
        _Pragma("unroll")                                                      \
        for (int ni_ = 0; ni_ < 4; ++ni_)                                      \
            acc[mi_][ni_] = __builtin_amdgcn_mfma_scale_f32_16x16x128_f8f6f4(  \
                af_[mi_], bf[ni_], acc[mi_][ni_],                              \
                0, 0,                       /* cbsz=FP8, blgp=FP8 */           \
                0, 0x7f7f7f7f,              /* scale_a = 1.0 */                \
                0, 0x7f7f7f7f);             /* scale_b = 1.0 */                \
    __builtin_amdgcn_s_setprio(0);

    // ---- prologue
    STAGE_B(0, 0);
    LOAD_AF(afA, 0);
    WAITVM(0);
    BAR();

    const int NT = K / BKB;           // 8 K-tiles; unrolled x2 (even=buf0, odd=buf1)
    for (int tt = 0; tt < NT; tt += 2) {
        // ---- tile tt (buf 0), uses afA
        if (tt + 1 < NT) {
            STAGE_B(tt + 1, 1);
            LOAD_AF(afB, tt + 1);
        }
        LOAD_BF(Bls);
        MFMA_ALL(afA);
        WAITVM(0);                    // drains B-stage + afB (robust: all vmem)
        BAR();

        // ---- tile tt+1 (buf 1), uses afB
        if (tt + 2 < NT) {
            STAGE_B(tt + 2, 0);
            LOAD_AF(afA, tt + 2);
        }
        LOAD_BF(Bls + BTILE);
        MFMA_ALL(afB);
        if (tt + 2 < NT) {
            WAITVM(0);
            BAR();
        }
    }

    // epilogue: C[row][col] = 4*acc + xxh[row] + mmh[col]
    int rowb = tn * 128 + wr * 64;
    int colb = tm * 128 + wc * 64;
#pragma unroll
    for (int mi = 0; mi < 4; ++mi) {
        float xh[4];
#pragma unroll
        for (int j = 0; j < 4; ++j) xh[j] = xxh[rowb + mi * 16 + lk * 4 + j];
#pragma unroll
        for (int ni = 0; ni < 4; ++ni) {
            int col = colb + ni * 16 + r;
            float mh = mmh[col];
#pragma unroll
            for (int j = 0; j < 4; ++j) {
                int row = rowb + mi * 16 + lk * 4 + j;
                C[(size_t)row * M + col] = acc[mi][ni][j] * 4.0f + xh[j] + mh;
            }
        }
    }
#undef STAGE_B
#undef LOAD_AF
#undef LOAD_BF
#undef MFMA_ALL
}

extern "C" void kernel_launch(void* const* d_in, const int* in_sizes, int n_in,
                              void* d_out, int out_size, void* d_ws, size_t ws_size,
                              hipStream_t stream) {
    const float* x    = (const float*)d_in[0];
    const float* mu   = (const float*)d_in[1];
    const float* stdv = (const float*)d_in[2];
    float* out = (float*)d_out;

    char* ws = (char*)d_ws;
    unsigned char* Ap  = (unsigned char*)ws;                        // N*K = 16 MB (fragment layout)
    unsigned char* Wb8 = (unsigned char*)(ws + (size_t)N * K);      // M*K = 1 MB
    float* xxh = (float*)(ws + (size_t)N * K + (size_t)M * K);      // 64 KB
    float* mmh = (float*)((char*)xxh + (size_t)N * sizeof(float));  // 4 KB

    prep_mu<<<M, 256, 0, stream>>>(mu, stdv, (uint32*)Wb8, mmh);
    prep_x<<<N / 16, 256, 0, stream>>>(x, stdv, Ap, xxh);
    gemm_ep<<<(N / 128) * (M / 128), 256, 0, stream>>>(Ap, Wb8, xxh, mmh, out);
}

// Round 11
// 52.550 us; speedup vs baseline: 2.3623x; 2.3623x over previous
//
#include <hip/hip_runtime.h>

typedef __attribute__((ext_vector_type(8))) int   i32x8;
typedef __attribute__((ext_vector_type(4))) float f32x4;
typedef unsigned int uint32;

constexpr int N = 16384;
constexpr int K = 1024;
constexpr int M = 1024;

#define WAITVM(n) asm volatile("s_waitcnt vmcnt(" #n ")" ::: "memory")
#define FENCE() asm volatile("" ::: "memory")
#define BAR()                          \
    do {                               \
        FENCE();                       \
        __builtin_amdgcn_s_barrier();  \
        FENCE();                       \
    } while (0)

__device__ inline void gload_lds16(const unsigned char* g, unsigned char* l) {
    __builtin_amdgcn_global_load_lds(
        (const __attribute__((address_space(1))) unsigned int*)g,
        (__attribute__((address_space(3))) unsigned int*)l,
        16, 0, 0);
}

// pack 4 f32 -> 4 OCP e4m3 bytes (k-ascending), saturating
__device__ inline uint32 pack4_fp8(float a, float b, float c, float d) {
    int v = __builtin_amdgcn_cvt_pk_fp8_f32(a, b, 0, false);   // bytes 0,1
    v = __builtin_amdgcn_cvt_pk_fp8_f32(c, d, v, true);        // bytes 2,3
    return (uint32)v;
}

// ---------------------------------------------------------------------------
// prep_mu: one block per mu row m. Normalizes, folds inv_std and the 1/4 fp8
// range scale, and writes W directly in MFMA-FRAGMENT layout:
//   Bp[g][kt][lane][j] = fp8(W[g*16+(lane&15)][kt*128+(lane>>4)*32+j])
// Thread t holds cols t*4..t*4+3 of row m -> one uint32 store at
//   ((g*8+kt)*64+lane)*32 + j  (consecutive t -> contiguous bytes, coalesced).
// Also mmh[m] = -0.5*sum(mu_n^2*inv_std).
// ---------------------------------------------------------------------------
__global__ void prep_mu(const float* __restrict__ mu, const float* __restrict__ stdv,
                        unsigned char* __restrict__ Bp, float* __restrict__ mmh) {
    int m = blockIdx.x;
    int t = threadIdx.x;
    float4 v = ((const float4*)(mu + (size_t)m * K))[t];
    float4 s = ((const float4*)stdv)[t];
    float ix = 1.0f / s.x, iy = 1.0f / s.y, iz = 1.0f / s.z, iw = 1.0f / s.w;
    float sum2  = v.x * v.x + v.y * v.y + v.z * v.z + v.w * v.w;
    float sum2w = v.x * v.x * ix + v.y * v.y * iy + v.z * v.z * iz + v.w * v.w * iw;
    for (int off = 32; off > 0; off >>= 1) {
        sum2  += __shfl_down(sum2, off, 64);
        sum2w += __shfl_down(sum2w, off, 64);
    }
    __shared__ float r2[4], r2w[4];
    __shared__ float s_scale;
    int lane = t & 63, w = t >> 6;
    if (lane == 0) { r2[w] = sum2; r2w[w] = sum2w; }
    __syncthreads();
    if (t == 0) {
        float tot2  = r2[0] + r2[1] + r2[2] + r2[3];
        float tot2w = r2w[0] + r2w[1] + r2w[2] + r2w[3];
        mmh[m] = -0.5f * tot2w / tot2;
        s_scale = rsqrtf(tot2) * 0.25f;        // fold the 1/4 fp8-range scale
    }
    __syncthreads();
    float sc = s_scale;
    // fragment-layout store address for cols t*4 .. t*4+3 of row m
    int col0 = t * 4;
    int kt = col0 >> 7;                 // 0..7
    int lk = (col0 >> 5) & 3;           // 0..3
    int j  = col0 & 31;                 // byte offset within 32B chunk
    int fl = (m & 15) + lk * 16;        // fragment lane
    int g  = m >> 4;
    uint32* dst = (uint32*)(Bp + ((size_t)((g * 8 + kt) * 64 + fl)) * 32 + j);
    *dst = pack4_fp8(v.x * ix * sc, v.y * iy * sc, v.z * iz * sc, v.w * iw * sc);
}

// Wave-per-row: x->fp8 (row-major), xxh = -0.5*sum(x^2/std). No barriers/LDS.
__global__ __launch_bounds__(256) void prep_x(const float* __restrict__ x,
                                              const float* __restrict__ stdv,
                                              uint32* __restrict__ xb8,
                                              float* __restrict__ xxh) {
    int row = blockIdx.x * 4 + (threadIdx.x >> 6);
    int lane = threadIdx.x & 63;
    const float4* src = (const float4*)(x + (size_t)row * K);
    const float4* sp  = (const float4*)stdv;
    uint32* dst = xb8 + (size_t)row * (K / 4);
    float ssum = 0.f;
#pragma unroll
    for (int i = 0; i < 4; ++i) {
        int idx = lane + 64 * i;
        float4 v = src[idx];
        float4 s = sp[idx];
        ssum += v.x * v.x / s.x + v.y * v.y / s.y + v.z * v.z / s.z + v.w * v.w / s.w;
        dst[idx] = pack4_fp8(v.x, v.y, v.z, v.w);
    }
#pragma unroll
    for (int off = 32; off > 0; off >>= 1) ssum += __shfl_down(ssum, off, 64);
    if (lane == 0) xxh[row] = -0.5f * ssum;
}

// ---------------------------------------------------------------------------
// fp8 GEMM, 128x128 tile, 4 waves (2x2, 64x64 each), BK=128 bytes.
// A: global_load_lds dbuf (32 KiB), slot^(row&7) swizzle (rule 21) — R4-proven.
// B: fragment-layout B' (1 MB, L2-resident) loaded DIRECT to registers with
//    coalesced dwordx4 (no LDS) — halves per-tile LDS traffic (96->48 KB).
//    bf loads issued BEFORE the A stage so their auto-vmcnt wait leaves the
//    stage loads in flight. Single fragment set (no reg-dbuf; R9 spill lesson).
// All waits are vmcnt(0) DRAINS (replay-safe). 3 blocks/CU target.
// C = 4*(A8*B'^T) + xxh[row] + mmh[col]
// ---------------------------------------------------------------------------
#define BKB 128
#define ATILE (128 * BKB)              // 16 KiB per A buffer

__global__ __launch_bounds__(256, 3) void gemm_ep(
    const unsigned char* __restrict__ A8, const unsigned char* __restrict__ Bp,
    const float* __restrict__ xxh, const float* __restrict__ mmh,
    float* __restrict__ C) {
    __shared__ unsigned char Als[2 * ATILE];   // 32 KiB

    int t = threadIdx.x;
    int lane = t & 63;
    int wave = t >> 6;
    int wr = wave >> 1;          // 0..1
    int wc = wave & 1;           // 0..1
    int r  = lane & 15;
    int lk = lane >> 4;          // k-slot 0..3 (32B each)

    // T1: XCD swizzle, nwg=1024 (bijective: 1024%8==0)
    int bid = blockIdx.x;
    int swz = (bid & 7) * 128 + (bid >> 3);
    int tn = swz >> 3;           // 0..127
    int tm = swz & 7;            // 0..7

    const unsigned char* Abase = A8 + (size_t)tn * 128 * K;
    // B' base for this wave: fragment group g2 = tm*8 + wc*4 + ni,
    // chunk addr = ((g2*8 + kt)*64 + lane)*32 = g2*16384 + kt*2048 + lane*32
    const unsigned char* Bw = Bp + (size_t)(tm * 8 + wc * 4) * 16384 + (size_t)lane * 32;

    f32x4 acc[4][4] = {};
    i32x8 af[4], bf[4];

    // stage one 128x128B A tile: 1024 16B chunks, 4 per thread.
    // lds row=c>>3, slot=c&7; SOURCE slot pre-swizzled ^(row&7) (rule 21).
#define STAGE_A(kt_, buf_)                                                     \
    {                                                                          \
        const unsigned char* g_ = Abase + (size_t)(kt_) * BKB;                 \
        unsigned char* l_ = Als + (buf_) * ATILE;                              \
        _Pragma("unroll")                                                      \
        for (int i_ = 0; i_ < 4; ++i_) {                                       \
            int c_ = i_ * 256 + t;                                             \
            int row_ = c_ >> 3;                                                \
            int slot_ = (c_ & 7) ^ (row_ & 7);                                 \
            gload_lds16(g_ + (size_t)row_ * K + slot_ * 16,                    \
                        l_ + (i_ * 256 + (wave << 6)) * 16);                   \
        }                                                                      \
    }

    // ---- prologue
    STAGE_A(0, 0);
    WAITVM(0);
    BAR();

    const int NT = K / BKB;           // 8 K-tiles
    for (int kt = 0; kt < NT; ++kt) {
        int cur = kt & 1;
        const unsigned char* As = Als + cur * ATILE;

        // B fragments direct from L2-resident B' (issue FIRST: their auto
        // vmcnt wait then leaves the A-stage loads below still in flight)
#pragma unroll
        for (int ni = 0; ni < 4; ++ni) {
            const unsigned char* gb = Bw + (size_t)ni * 16384 + (size_t)kt * 2048;
            uint4 q0 = *(const uint4*)gb;
            uint4 q1 = *(const uint4*)(gb + 16);
            bf[ni][0] = q0.x; bf[ni][1] = q0.y; bf[ni][2] = q0.z; bf[ni][3] = q0.w;
            bf[ni][4] = q1.x; bf[ni][5] = q1.y; bf[ni][6] = q1.z; bf[ni][7] = q1.w;
        }

        // prefetch next A-tile into the other buffer (disjoint from reads)
        if (kt + 1 < NT) STAGE_A(kt + 1, cur ^ 1);

        // A fragments from swizzled LDS: byte slots (2lk|h)^(r&7)
#pragma unroll
        for (int mi = 0; mi < 4; ++mi) {
            int row = wr * 64 + mi * 16 + r;
            uint4 q0 = *(const uint4*)&As[(row << 7) + ((((lk << 1) | 0) ^ (r & 7)) << 4)];
            uint4 q1 = *(const uint4*)&As[(row << 7) + ((((lk << 1) | 1) ^ (r & 7)) << 4)];
            af[mi][0] = q0.x; af[mi][1] = q0.y; af[mi][2] = q0.z; af[mi][3] = q0.w;
            af[mi][4] = q1.x; af[mi][5] = q1.y; af[mi][6] = q1.z; af[mi][7] = q1.w;
        }

        __builtin_amdgcn_s_setprio(1);
#pragma unroll
        for (int mi = 0; mi < 4; ++mi)
#pragma unroll
            for (int ni = 0; ni < 4; ++ni)
                acc[mi][ni] = __builtin_amdgcn_mfma_scale_f32_16x16x128_f8f6f4(
                    af[mi], bf[ni], acc[mi][ni],
                    0, 0,                       // cbsz=FP8, blgp=FP8
                    0, 0x7f7f7f7f,              // scale_a = 1.0
                    0, 0x7f7f7f7f);             // scale_b = 1.0
        __builtin_amdgcn_s_setprio(0);

        // drain the A prefetch (robust: retires ALL vmem incl. any spills)
        if (kt + 1 < NT) WAITVM(0);
        BAR();
    }

    // epilogue: C[row][col] = 4*acc + xxh[row] + mmh[col]
    int rowb = tn * 128 + wr * 64;
    int colb = tm * 128 + wc * 64;
#pragma unroll
    for (int mi = 0; mi < 4; ++mi) {
        float xh[4];
#pragma unroll
        for (int j = 0; j < 4; ++j) xh[j] = xxh[rowb + mi * 16 + lk * 4 + j];
#pragma unroll
        for (int ni = 0; ni < 4; ++ni) {
            int col = colb + ni * 16 + r;
            float mh = mmh[col];
#pragma unroll
            for (int j = 0; j < 4; ++j) {
                int row = rowb + mi * 16 + lk * 4 + j;
                C[(size_t)row * M + col] = acc[mi][ni][j] * 4.0f + xh[j] + mh;
            }
        }
    }
#undef STAGE_A
}

extern "C" void kernel_launch(void* const* d_in, const int* in_sizes, int n_in,
                              void* d_out, int out_size, void* d_ws, size_t ws_size,
                              hipStream_t stream) {
    const float* x    = (const float*)d_in[0];
    const float* mu   = (const float*)d_in[1];
    const float* stdv = (const float*)d_in[2];
    float* out = (float*)d_out;

    char* ws = (char*)d_ws;
    unsigned char* xb8 = (unsigned char*)ws;                        // N*K = 16 MB (row-major fp8)
    unsigned char* Bp  = (unsigned char*)(ws + (size_t)N * K);      // M*K = 1 MB (fragment layout)
    float* xxh = (float*)(ws + (size_t)N * K + (size_t)M * K);      // 64 KB
    float* mmh = (float*)((char*)xxh + (size_t)N * sizeof(float));  // 4 KB

    prep_mu<<<M, 256, 0, stream>>>(mu, stdv, Bp, mmh);
    prep_x<<<N / 4, 256, 0, stream>>>(x, stdv, (uint32*)xb8, xxh);
    gemm_ep<<<(N / 128) * (M / 128), 256, 0, stream>>>(xb8, Bp, xxh, mmh, out);
}